// Round 5
// baseline (254.478 us; speedup 1.0000x reference)
//
#include <hip/hip_runtime.h>
#include <math.h>

// CapsuleLinear dynamic routing, priors never materialized.
//   s[b,o,i]   = sum_n prob[b,o,n] * x[b,n,i]
//   out[b,o,l] = sum_i W[o,l,i] * s[b,o,i]
//   logits[b,o,n] = x[b,n,:] . T[b,o,:],  T accumulates W^T(squash(u_r)) per round
//
// 5 plain stream-ordered dispatches (coherence = dispatch boundaries; no
// fences/global atomics/tickets — R3/R4 showed those cost ~35us/dispatch):
//   k_init -> k_pass(T1) -> k_mid -> k_pass(T2) -> k_out
// k_pass: lane = o, wave softmax over 64 lanes, 2 independent n-chains for
// latency hiding, conflict-free transposed LDS s-tile (ds_add_f32).

#define N_B      32
#define IN_CAPS  1152
#define IN_LEN   32
#define OUT_CAPS 64
#define OUT_LEN  32
#define NCHUNK   36                  // grid (36, 32) -> 1152 blocks
#define NPB      (IN_CAPS / NCHUNK)  // 32 n per block
#define NPW      (NPB / 4)           // 8 n per wave

__device__ __forceinline__ float4 f4fma(const float4 a, const float4 b, float4 c) {
    c.x = fmaf(a.x, b.x, c.x); c.y = fmaf(a.y, b.y, c.y);
    c.z = fmaf(a.z, b.z, c.z); c.w = fmaf(a.w, b.w, c.w);
    return c;
}
__device__ __forceinline__ float f4hsum(const float4 a) { return (a.x + a.y) + (a.z + a.w); }

// ---------------------------------------------------------------------------
// k_init: s0 = (1/64) sum_n x[b,n,:]; u = W@s0; v = squash(u); T1 = W^T@v
// ---------------------------------------------------------------------------
__global__ __launch_bounds__(256) void k_init(const float* __restrict__ x,
                                              const float* __restrict__ W,
                                              float* __restrict__ T1) {
    const int b   = blockIdx.x;
    const int tid = threadIdx.x;
    const float* xb = x + (size_t)b * IN_CAPS * IN_LEN;

    __shared__ float4 red4[32][8];
    {
        const int q = tid & 7, g = tid >> 3;
        float4 acc = make_float4(0.f, 0.f, 0.f, 0.f);
        for (int n = g; n < IN_CAPS; n += 32) {
            const float4 v = ((const float4*)(xb + n * IN_LEN))[q];
            acc.x += v.x; acc.y += v.y; acc.z += v.z; acc.w += v.w;
        }
        red4[g][q] = acc;
    }
    __syncthreads();
    __shared__ float s0[IN_LEN];
    if (tid < 8) {
        float4 v = make_float4(0.f, 0.f, 0.f, 0.f);
        for (int g = 0; g < 32; ++g) {
            const float4 r = red4[g][tid];
            v.x += r.x; v.y += r.y; v.z += r.z; v.w += r.w;
        }
        const float inv = 1.f / 64.f;   // uniform routing probs at r=0
        s0[tid * 4 + 0] = v.x * inv;
        s0[tid * 4 + 1] = v.y * inv;
        s0[tid * 4 + 2] = v.z * inv;
        s0[tid * 4 + 3] = v.w * inv;
    }
    __syncthreads();

    __shared__ float u[OUT_CAPS * OUT_LEN];
    for (int e = tid; e < OUT_CAPS * OUT_LEN; e += 256) {
        const float4* wr = (const float4*)(W + (size_t)e * IN_LEN);
        const float4* sr = (const float4*)s0;
        float4 a4 = make_float4(0.f, 0.f, 0.f, 0.f);
#pragma unroll
        for (int q = 0; q < 8; ++q) a4 = f4fma(wr[q], sr[q], a4);
        u[e] = f4hsum(a4);
    }
    __syncthreads();

    __shared__ float scale[OUT_CAPS];
    if (tid < OUT_CAPS) {
        float ns = 0.f;
#pragma unroll
        for (int l = 0; l < OUT_LEN; ++l) { const float v = u[tid * OUT_LEN + l]; ns = fmaf(v, v, ns); }
        scale[tid] = sqrtf(ns) / (1.f + ns);
    }
    __syncthreads();

    for (int e = tid; e < OUT_CAPS * IN_LEN; e += 256) {
        const int o = e >> 5, i = e & 31;
        float a = 0.f;
#pragma unroll
        for (int l = 0; l < OUT_LEN; ++l)
            a = fmaf(W[(size_t)(o * OUT_LEN + l) * IN_LEN + i], u[o * OUT_LEN + l], a);
        T1[(size_t)b * OUT_CAPS * IN_LEN + e] = a * scale[o];
    }
}

// ---------------------------------------------------------------------------
// k_pass: block (c, b). lane = o. Per n: logit = x.T (fp32 dot in regs),
// softmax over 64 lanes (no max-shift: |logit| <~ 70, fp32-safe),
// s accumulate in regs. Two independent n-chains per iteration for latency
// hiding. End: conflict-free ds_add into transposed stile[i][o], then
// coalesced partial store: part[(b*36+c)][i*64+o].
// ---------------------------------------------------------------------------
__global__ __launch_bounds__(256, 3) void k_pass(const float* __restrict__ x,
                                                 const float* __restrict__ Tsrc,
                                                 float* __restrict__ part) {
    const int c    = blockIdx.x;        // 0..35
    const int b    = blockIdx.y;        // 0..31
    const int tid  = threadIdx.x;
    const int lane = tid & 63;          // = output capsule o
    const int wave = tid >> 6;

    __shared__ __align__(16) float stile[IN_LEN * OUT_CAPS];  // 8 KB, [i][o]
    for (int e = tid; e < IN_LEN * OUT_CAPS; e += 256) stile[e] = 0.f;
    __syncthreads();

    float4 t4[8], s4[8];
    {
        const float4* Trow = (const float4*)(Tsrc + ((size_t)b * OUT_CAPS + lane) * IN_LEN);
#pragma unroll
        for (int q = 0; q < 8; ++q) { t4[q] = Trow[q]; s4[q] = make_float4(0.f, 0.f, 0.f, 0.f); }
    }

    const float* xp = x + (size_t)(b * IN_CAPS + c * NPB + wave * NPW) * IN_LEN;
#pragma unroll
    for (int j = 0; j < NPW; j += 2) {
        const float4* x0 = (const float4*)(xp + j * IN_LEN);
        const float4* x1 = (const float4*)(xp + (j + 1) * IN_LEN);
        float4 xa[8], xb[8];
#pragma unroll
        for (int q = 0; q < 8; ++q) { xa[q] = x0[q]; xb[q] = x1[q]; }

        float4 d0 = make_float4(0.f, 0.f, 0.f, 0.f);
        float4 d1 = make_float4(0.f, 0.f, 0.f, 0.f);
#pragma unroll
        for (int q = 0; q < 8; ++q) { d0 = f4fma(xa[q], t4[q], d0); d1 = f4fma(xb[q], t4[q], d1); }
        const float l0 = f4hsum(d0), l1 = f4hsum(d1);

        const float e0 = __expf(l0), e1 = __expf(l1);
        float z0 = e0, z1 = e1;
#pragma unroll
        for (int off = 32; off >= 1; off >>= 1) {   // two independent shfl chains
            z0 += __shfl_xor(z0, off, 64);
            z1 += __shfl_xor(z1, off, 64);
        }
        const float pr0 = e0 / z0, pr1 = e1 / z1;
        const float4 p0v = make_float4(pr0, pr0, pr0, pr0);
        const float4 p1v = make_float4(pr1, pr1, pr1, pr1);
#pragma unroll
        for (int q = 0; q < 8; ++q) {
            s4[q] = f4fma(p0v, xa[q], s4[q]);
            s4[q] = f4fma(p1v, xb[q], s4[q]);
        }
    }

    // conflict-free cross-wave accumulate: stile[i][o], lane stride 4 B
#pragma unroll
    for (int q = 0; q < 8; ++q) {
        atomicAdd(&stile[(q * 4 + 0) * OUT_CAPS + lane], s4[q].x);
        atomicAdd(&stile[(q * 4 + 1) * OUT_CAPS + lane], s4[q].y);
        atomicAdd(&stile[(q * 4 + 2) * OUT_CAPS + lane], s4[q].z);
        atomicAdd(&stile[(q * 4 + 3) * OUT_CAPS + lane], s4[q].w);
    }
    __syncthreads();

    // coalesced partial store (transposed layout preserved)
    {
        const float4* st4 = (const float4*)stile;
        float4* pb4 = (float4*)(part + ((size_t)b * NCHUNK + c) * (IN_LEN * OUT_CAPS));
        for (int e = tid; e < IN_LEN * OUT_CAPS / 4; e += 256) pb4[e] = st4[e];
    }
}

// ---------------------------------------------------------------------------
// k_mid: s = sum_c part[b,c] (transposed [i][o]); u = W@s; v = squash(u);
//        T2 = T1 + W^T@v
// ---------------------------------------------------------------------------
__global__ __launch_bounds__(256) void k_mid(const float* __restrict__ W,
                                             const float* __restrict__ part,
                                             const float* __restrict__ T1,
                                             float* __restrict__ T2) {
    const int b   = blockIdx.x;
    const int tid = threadIdx.x;

    __shared__ __align__(16) float s_l[IN_LEN * OUT_CAPS];   // [i][o]
    {
        const float4* pb = (const float4*)(part + (size_t)b * NCHUNK * (IN_LEN * OUT_CAPS));
        for (int e = tid; e < IN_LEN * OUT_CAPS / 4; e += 256) {
            float4 a = make_float4(0.f, 0.f, 0.f, 0.f);
            for (int cc = 0; cc < NCHUNK; ++cc) {
                const float4 v = pb[cc * (IN_LEN * OUT_CAPS / 4) + e];
                a.x += v.x; a.y += v.y; a.z += v.z; a.w += v.w;
            }
            ((float4*)s_l)[e] = a;
        }
    }
    __syncthreads();

    __shared__ float u_l[OUT_CAPS * OUT_LEN];
    for (int e = tid; e < OUT_CAPS * OUT_LEN; e += 256) {
        const int o = e >> 5;
        const float* wr = W + (size_t)e * IN_LEN;
        float a = 0.f;
#pragma unroll
        for (int i = 0; i < IN_LEN; ++i) a = fmaf(wr[i], s_l[i * OUT_CAPS + o], a);
        u_l[e] = a;
    }
    __syncthreads();

    __shared__ float sc_l[OUT_CAPS];
    if (tid < OUT_CAPS) {
        float ns = 0.f;
#pragma unroll
        for (int l = 0; l < OUT_LEN; ++l) { const float v = u_l[tid * OUT_LEN + l]; ns = fmaf(v, v, ns); }
        sc_l[tid] = sqrtf(ns) / (1.f + ns);
    }
    __syncthreads();

    for (int e = tid; e < OUT_CAPS * IN_LEN; e += 256) {
        const int o = e >> 5, i = e & 31;
        float a = 0.f;
#pragma unroll
        for (int l = 0; l < OUT_LEN; ++l)
            a = fmaf(W[(size_t)(o * OUT_LEN + l) * IN_LEN + i], u_l[o * OUT_LEN + l], a);
        T2[(size_t)b * OUT_CAPS * IN_LEN + e] = T1[(size_t)b * OUT_CAPS * IN_LEN + e] + a * sc_l[o];
    }
}

// ---------------------------------------------------------------------------
// k_out: s = sum_c part[b,c]; u = W@s; out = squash(u)
// ---------------------------------------------------------------------------
__global__ __launch_bounds__(256) void k_out(const float* __restrict__ W,
                                             const float* __restrict__ part,
                                             float* __restrict__ out) {
    const int b   = blockIdx.x;
    const int tid = threadIdx.x;

    __shared__ __align__(16) float s_l[IN_LEN * OUT_CAPS];   // [i][o]
    {
        const float4* pb = (const float4*)(part + (size_t)b * NCHUNK * (IN_LEN * OUT_CAPS));
        for (int e = tid; e < IN_LEN * OUT_CAPS / 4; e += 256) {
            float4 a = make_float4(0.f, 0.f, 0.f, 0.f);
            for (int cc = 0; cc < NCHUNK; ++cc) {
                const float4 v = pb[cc * (IN_LEN * OUT_CAPS / 4) + e];
                a.x += v.x; a.y += v.y; a.z += v.z; a.w += v.w;
            }
            ((float4*)s_l)[e] = a;
        }
    }
    __syncthreads();

    __shared__ float u_l[OUT_CAPS * OUT_LEN];
    for (int e = tid; e < OUT_CAPS * OUT_LEN; e += 256) {
        const int o = e >> 5;
        const float* wr = W + (size_t)e * IN_LEN;
        float a = 0.f;
#pragma unroll
        for (int i = 0; i < IN_LEN; ++i) a = fmaf(wr[i], s_l[i * OUT_CAPS + o], a);
        u_l[e] = a;
    }
    __syncthreads();

    __shared__ float sc_l[OUT_CAPS];
    if (tid < OUT_CAPS) {
        float ns = 0.f;
#pragma unroll
        for (int l = 0; l < OUT_LEN; ++l) { const float v = u_l[tid * OUT_LEN + l]; ns = fmaf(v, v, ns); }
        sc_l[tid] = sqrtf(ns) / (1.f + ns);
    }
    __syncthreads();

    for (int e = tid; e < OUT_CAPS * OUT_LEN; e += 256)
        out[(size_t)b * (OUT_CAPS * OUT_LEN) + e] = u_l[e] * sc_l[e >> 5];
}

extern "C" void kernel_launch(void* const* d_in, const int* in_sizes, int n_in,
                              void* d_out, int out_size, void* d_ws, size_t ws_size,
                              hipStream_t stream) {
    const float* x = (const float*)d_in[0];   // [32,1152,32]
    const float* W = (const float*)d_in[1];   // [64,32,32]
    float* out = (float*)d_out;               // [32,64,32]

    float* T1   = (float*)d_ws;                               // 65536 floats (256 KB)
    float* T2   = T1 + (size_t)N_B * OUT_CAPS * IN_LEN;       // 65536 floats
    float* part = T2 + (size_t)N_B * OUT_CAPS * IN_LEN;       // 32*36*2048 floats (9.4 MB)

    k_init<<<N_B, 256, 0, stream>>>(x, W, T1);
    k_pass<<<dim3(NCHUNK, N_B), 256, 0, stream>>>(x, T1, part);   // routing iter 1
    k_mid <<<N_B, 256, 0, stream>>>(W, part, T1, T2);
    k_pass<<<dim3(NCHUNK, N_B), 256, 0, stream>>>(x, T2, part);   // routing iter 2
    k_out <<<N_B, 256, 0, stream>>>(W, part, out);
}

// Round 6
// 166.972 us; speedup vs baseline: 1.5241x; 1.5241x over previous
//
#include <hip/hip_runtime.h>
#include <math.h>

// CapsuleLinear dynamic routing, priors never materialized.
//   s[b,o,i]   = sum_n prob[b,o,n] * x[b,n,i]
//   out[b,o,l] = sum_i W[o,l,i] * s[b,o,i]
//   logits[b,o,n] = x[b,n,:] . T[b,o,:],  T accumulates W^T(squash(u_r)) per round
//
// 5 plain stream-ordered dispatches: k_init -> k_pass -> k_mid -> k_pass -> k_out.
//
// CRITICAL (R3-R5 post-mortem): `wave` MUST be readfirstlane'd to an SGPR so the
// wave-uniform x pointer is provably uniform and x fetches compile to SCALAR
// (SMEM) loads. With a VGPR pointer, each load pushes 64 identical addresses
// through the per-CU TA (~64 cyc/instr, shared across waves -> no latency
// hiding): measured 73us vs ~35us for the identical loop with SGPR base.

#define N_B      32
#define IN_CAPS  1152
#define IN_LEN   32
#define OUT_CAPS 64
#define OUT_LEN  32
#define NCHUNK   16                  // grid (16, 32) -> 512 blocks
#define NPB      (IN_CAPS / NCHUNK)  // 72 n per block
#define NPW      (NPB / 4)           // 18 n per wave

__device__ __forceinline__ float4 f4fma(const float4 a, const float4 b, float4 c) {
    c.x = fmaf(a.x, b.x, c.x); c.y = fmaf(a.y, b.y, c.y);
    c.z = fmaf(a.z, b.z, c.z); c.w = fmaf(a.w, b.w, c.w);
    return c;
}
__device__ __forceinline__ float f4hsum(const float4 a) { return (a.x + a.y) + (a.z + a.w); }

// ---------------------------------------------------------------------------
// k_init: s0 = (1/64) sum_n x[b,n,:]; u = W@s0; v = squash(u); T1 = W^T@v
// ---------------------------------------------------------------------------
__global__ __launch_bounds__(256) void k_init(const float* __restrict__ x,
                                              const float* __restrict__ W,
                                              float* __restrict__ T1) {
    const int b   = blockIdx.x;
    const int tid = threadIdx.x;
    const float* xb = x + (size_t)b * IN_CAPS * IN_LEN;

    __shared__ float4 red4[32][8];
    {
        const int q = tid & 7, g = tid >> 3;   // g = 0..31
        float4 a0 = make_float4(0.f, 0.f, 0.f, 0.f), a1 = a0, a2 = a0, a3 = a0;
        for (int n = g; n < IN_CAPS; n += 128) {   // 9 iters, 4 independent loads
            const float4 v0 = ((const float4*)(xb + (n +  0) * IN_LEN))[q];
            const float4 v1 = ((const float4*)(xb + (n + 32) * IN_LEN))[q];
            const float4 v2 = ((const float4*)(xb + (n + 64) * IN_LEN))[q];
            const float4 v3 = ((const float4*)(xb + (n + 96) * IN_LEN))[q];
            a0.x += v0.x; a0.y += v0.y; a0.z += v0.z; a0.w += v0.w;
            a1.x += v1.x; a1.y += v1.y; a1.z += v1.z; a1.w += v1.w;
            a2.x += v2.x; a2.y += v2.y; a2.z += v2.z; a2.w += v2.w;
            a3.x += v3.x; a3.y += v3.y; a3.z += v3.z; a3.w += v3.w;
        }
        a0.x += a1.x + a2.x + a3.x; a0.y += a1.y + a2.y + a3.y;
        a0.z += a1.z + a2.z + a3.z; a0.w += a1.w + a2.w + a3.w;
        red4[g][q] = a0;
    }
    __syncthreads();
    __shared__ float s0[IN_LEN];
    if (tid < 8) {
        float4 v = make_float4(0.f, 0.f, 0.f, 0.f);
        for (int g = 0; g < 32; ++g) {
            const float4 r = red4[g][tid];
            v.x += r.x; v.y += r.y; v.z += r.z; v.w += r.w;
        }
        const float inv = 1.f / 64.f;   // uniform routing probs at r=0
        s0[tid * 4 + 0] = v.x * inv;
        s0[tid * 4 + 1] = v.y * inv;
        s0[tid * 4 + 2] = v.z * inv;
        s0[tid * 4 + 3] = v.w * inv;
    }
    __syncthreads();

    __shared__ float u[OUT_CAPS * OUT_LEN];
    for (int e = tid; e < OUT_CAPS * OUT_LEN; e += 256) {
        const float4* wr = (const float4*)(W + (size_t)e * IN_LEN);
        const float4* sr = (const float4*)s0;
        float4 a4 = make_float4(0.f, 0.f, 0.f, 0.f);
#pragma unroll
        for (int q = 0; q < 8; ++q) a4 = f4fma(wr[q], sr[q], a4);
        u[e] = f4hsum(a4);
    }
    __syncthreads();

    __shared__ float scale[OUT_CAPS];
    if (tid < OUT_CAPS) {
        float ns = 0.f;
#pragma unroll
        for (int l = 0; l < OUT_LEN; ++l) { const float v = u[tid * OUT_LEN + l]; ns = fmaf(v, v, ns); }
        scale[tid] = sqrtf(ns) / (1.f + ns);
    }
    __syncthreads();

    for (int e = tid; e < OUT_CAPS * IN_LEN; e += 256) {
        const int o = e >> 5, i = e & 31;
        float a = 0.f;
#pragma unroll
        for (int l = 0; l < OUT_LEN; ++l)
            a = fmaf(W[(size_t)(o * OUT_LEN + l) * IN_LEN + i], u[o * OUT_LEN + l], a);
        T1[(size_t)b * OUT_CAPS * IN_LEN + e] = a * scale[o];
    }
}

// ---------------------------------------------------------------------------
// k_pass: block (c, b), lane = o. Per n: logit = x.T (regs), softmax over the
// 64 lanes (no max-shift: |logit| <~ 70, fp32-safe), s accumulate in regs.
// x loads are SCALAR (SGPR base via readfirstlane). Epilogue: conflict-free
// ds_add into transposed stile[i][o], coalesced store to part[b,c][i][o].
// ---------------------------------------------------------------------------
__global__ __launch_bounds__(256) void k_pass(const float* __restrict__ x,
                                              const float* __restrict__ Tsrc,
                                              float* __restrict__ part) {
    const int c    = blockIdx.x;        // 0..15
    const int b    = blockIdx.y;        // 0..31
    const int tid  = threadIdx.x;
    const int lane = tid & 63;          // = output capsule o
    const int wave = __builtin_amdgcn_readfirstlane(tid >> 6);   // SGPR! (see header)

    __shared__ __align__(16) float stile[IN_LEN * OUT_CAPS];  // 8 KB, [i][o]
    for (int e = tid; e < IN_LEN * OUT_CAPS; e += 256) stile[e] = 0.f;
    __syncthreads();

    float4 t4[8], s4[8];
    {
        const float4* Trow = (const float4*)(Tsrc + ((size_t)b * OUT_CAPS + lane) * IN_LEN);
#pragma unroll
        for (int q = 0; q < 8; ++q) { t4[q] = Trow[q]; s4[q] = make_float4(0.f, 0.f, 0.f, 0.f); }
    }

    const float* xp = x + (size_t)(b * IN_CAPS + c * NPB + wave * NPW) * IN_LEN;
    for (int j = 0; j < NPW; j += 2) {
        const float4* x0 = (const float4*)(xp + j * IN_LEN);
        const float4* x1 = (const float4*)(xp + (j + 1) * IN_LEN);
        float4 xa[8], xb[8];
#pragma unroll
        for (int q = 0; q < 8; ++q) { xa[q] = x0[q]; xb[q] = x1[q]; }

        float4 d0 = make_float4(0.f, 0.f, 0.f, 0.f);
        float4 d1 = make_float4(0.f, 0.f, 0.f, 0.f);
#pragma unroll
        for (int q = 0; q < 8; ++q) { d0 = f4fma(xa[q], t4[q], d0); d1 = f4fma(xb[q], t4[q], d1); }
        const float l0 = f4hsum(d0), l1 = f4hsum(d1);

        const float e0 = __expf(l0), e1 = __expf(l1);
        float z0 = e0, z1 = e1;
#pragma unroll
        for (int off = 32; off >= 1; off >>= 1) {   // two independent shfl chains
            z0 += __shfl_xor(z0, off, 64);
            z1 += __shfl_xor(z1, off, 64);
        }
        const float pr0 = e0 / z0, pr1 = e1 / z1;
        const float4 p0v = make_float4(pr0, pr0, pr0, pr0);
        const float4 p1v = make_float4(pr1, pr1, pr1, pr1);
#pragma unroll
        for (int q = 0; q < 8; ++q) {
            s4[q] = f4fma(p0v, xa[q], s4[q]);
            s4[q] = f4fma(p1v, xb[q], s4[q]);
        }
    }

    // conflict-free cross-wave accumulate: stile[i][o], lane stride 4 B
#pragma unroll
    for (int q = 0; q < 8; ++q) {
        atomicAdd(&stile[(q * 4 + 0) * OUT_CAPS + lane], s4[q].x);
        atomicAdd(&stile[(q * 4 + 1) * OUT_CAPS + lane], s4[q].y);
        atomicAdd(&stile[(q * 4 + 2) * OUT_CAPS + lane], s4[q].z);
        atomicAdd(&stile[(q * 4 + 3) * OUT_CAPS + lane], s4[q].w);
    }
    __syncthreads();

    {
        const float4* st4 = (const float4*)stile;
        float4* pb4 = (float4*)(part + ((size_t)b * NCHUNK + c) * (IN_LEN * OUT_CAPS));
        for (int e = tid; e < IN_LEN * OUT_CAPS / 4; e += 256) pb4[e] = st4[e];
    }
}

// ---------------------------------------------------------------------------
// k_mid: s = sum_c part[b,c] ([i][o]); u = W@s; v = squash(u); T2 = T1 + W^T@v
// ---------------------------------------------------------------------------
__global__ __launch_bounds__(256) void k_mid(const float* __restrict__ W,
                                             const float* __restrict__ part,
                                             const float* __restrict__ T1,
                                             float* __restrict__ T2) {
    const int b   = blockIdx.x;
    const int tid = threadIdx.x;

    __shared__ __align__(16) float s_l[IN_LEN * OUT_CAPS];   // [i][o]
    {
        const float4* pb = (const float4*)(part + (size_t)b * NCHUNK * (IN_LEN * OUT_CAPS));
        for (int e = tid; e < IN_LEN * OUT_CAPS / 4; e += 256) {
            float4 a0 = make_float4(0.f, 0.f, 0.f, 0.f), a1 = a0, a2 = a0, a3 = a0;
#pragma unroll
            for (int cc = 0; cc < NCHUNK; cc += 4) {   // 4 independent chains
                const float4 v0 = pb[(cc + 0) * 512 + e];
                const float4 v1 = pb[(cc + 1) * 512 + e];
                const float4 v2 = pb[(cc + 2) * 512 + e];
                const float4 v3 = pb[(cc + 3) * 512 + e];
                a0.x += v0.x; a0.y += v0.y; a0.z += v0.z; a0.w += v0.w;
                a1.x += v1.x; a1.y += v1.y; a1.z += v1.z; a1.w += v1.w;
                a2.x += v2.x; a2.y += v2.y; a2.z += v2.z; a2.w += v2.w;
                a3.x += v3.x; a3.y += v3.y; a3.z += v3.z; a3.w += v3.w;
            }
            a0.x += a1.x + a2.x + a3.x; a0.y += a1.y + a2.y + a3.y;
            a0.z += a1.z + a2.z + a3.z; a0.w += a1.w + a2.w + a3.w;
            ((float4*)s_l)[e] = a0;
        }
    }
    __syncthreads();

    __shared__ float u_l[OUT_CAPS * OUT_LEN];
    for (int e = tid; e < OUT_CAPS * OUT_LEN; e += 256) {
        const int o = e >> 5;
        const float* wr = W + (size_t)e * IN_LEN;
        float a = 0.f;
#pragma unroll
        for (int i = 0; i < IN_LEN; ++i) a = fmaf(wr[i], s_l[i * OUT_CAPS + o], a);
        u_l[e] = a;
    }
    __syncthreads();

    __shared__ float sc_l[OUT_CAPS];
    if (tid < OUT_CAPS) {
        float ns = 0.f;
#pragma unroll
        for (int l = 0; l < OUT_LEN; ++l) { const float v = u_l[tid * OUT_LEN + l]; ns = fmaf(v, v, ns); }
        sc_l[tid] = sqrtf(ns) / (1.f + ns);
    }
    __syncthreads();

    for (int e = tid; e < OUT_CAPS * IN_LEN; e += 256) {
        const int o = e >> 5, i = e & 31;
        float a = 0.f;
#pragma unroll
        for (int l = 0; l < OUT_LEN; ++l)
            a = fmaf(W[(size_t)(o * OUT_LEN + l) * IN_LEN + i], u_l[o * OUT_LEN + l], a);
        T2[(size_t)b * OUT_CAPS * IN_LEN + e] = T1[(size_t)b * OUT_CAPS * IN_LEN + e] + a * sc_l[o];
    }
}

// ---------------------------------------------------------------------------
// k_out: s = sum_c part[b,c]; u = W@s; out = squash(u)
// ---------------------------------------------------------------------------
__global__ __launch_bounds__(256) void k_out(const float* __restrict__ W,
                                             const float* __restrict__ part,
                                             float* __restrict__ out) {
    const int b   = blockIdx.x;
    const int tid = threadIdx.x;

    __shared__ __align__(16) float s_l[IN_LEN * OUT_CAPS];   // [i][o]
    {
        const float4* pb = (const float4*)(part + (size_t)b * NCHUNK * (IN_LEN * OUT_CAPS));
        for (int e = tid; e < IN_LEN * OUT_CAPS / 4; e += 256) {
            float4 a0 = make_float4(0.f, 0.f, 0.f, 0.f), a1 = a0, a2 = a0, a3 = a0;
#pragma unroll
            for (int cc = 0; cc < NCHUNK; cc += 4) {
                const float4 v0 = pb[(cc + 0) * 512 + e];
                const float4 v1 = pb[(cc + 1) * 512 + e];
                const float4 v2 = pb[(cc + 2) * 512 + e];
                const float4 v3 = pb[(cc + 3) * 512 + e];
                a0.x += v0.x; a0.y += v0.y; a0.z += v0.z; a0.w += v0.w;
                a1.x += v1.x; a1.y += v1.y; a1.z += v1.z; a1.w += v1.w;
                a2.x += v2.x; a2.y += v2.y; a2.z += v2.z; a2.w += v2.w;
                a3.x += v3.x; a3.y += v3.y; a3.z += v3.z; a3.w += v3.w;
            }
            a0.x += a1.x + a2.x + a3.x; a0.y += a1.y + a2.y + a3.y;
            a0.z += a1.z + a2.z + a3.z; a0.w += a1.w + a2.w + a3.w;
            ((float4*)s_l)[e] = a0;
        }
    }
    __syncthreads();

    __shared__ float u_l[OUT_CAPS * OUT_LEN];
    for (int e = tid; e < OUT_CAPS * OUT_LEN; e += 256) {
        const int o = e >> 5;
        const float* wr = W + (size_t)e * IN_LEN;
        float a = 0.f;
#pragma unroll
        for (int i = 0; i < IN_LEN; ++i) a = fmaf(wr[i], s_l[i * OUT_CAPS + o], a);
        u_l[e] = a;
    }
    __syncthreads();

    __shared__ float sc_l[OUT_CAPS];
    if (tid < OUT_CAPS) {
        float ns = 0.f;
#pragma unroll
        for (int l = 0; l < OUT_LEN; ++l) { const float v = u_l[tid * OUT_LEN + l]; ns = fmaf(v, v, ns); }
        sc_l[tid] = sqrtf(ns) / (1.f + ns);
    }
    __syncthreads();

    for (int e = tid; e < OUT_CAPS * OUT_LEN; e += 256)
        out[(size_t)b * (OUT_CAPS * OUT_LEN) + e] = u_l[e] * sc_l[e >> 5];
}

extern "C" void kernel_launch(void* const* d_in, const int* in_sizes, int n_in,
                              void* d_out, int out_size, void* d_ws, size_t ws_size,
                              hipStream_t stream) {
    const float* x = (const float*)d_in[0];   // [32,1152,32]
    const float* W = (const float*)d_in[1];   // [64,32,32]
    float* out = (float*)d_out;               // [32,64,32]

    float* T1   = (float*)d_ws;                               // 65536 floats (256 KB)
    float* T2   = T1 + (size_t)N_B * OUT_CAPS * IN_LEN;       // 65536 floats
    float* part = T2 + (size_t)N_B * OUT_CAPS * IN_LEN;       // 32*16*2048 floats (4 MB)

    k_init<<<N_B, 256, 0, stream>>>(x, W, T1);
    k_pass<<<dim3(NCHUNK, N_B), 256, 0, stream>>>(x, T1, part);   // routing iter 1
    k_mid <<<N_B, 256, 0, stream>>>(W, part, T1, T2);
    k_pass<<<dim3(NCHUNK, N_B), 256, 0, stream>>>(x, T2, part);   // routing iter 2
    k_out <<<N_B, 256, 0, stream>>>(W, part, out);
}